// Round 1
// baseline (32503.751 us; speedup 1.0000x reference)
//
#include <hip/hip_runtime.h>
#include <hip/hip_fp16.h>

// LSTM N=64, T=1024, D=1024, H=1024. fp32 in/out, fp16 MFMA compute, fp32 accum.
//
// Plan:
//  k_cvt_x    : x fp32 -> x16 fp16 (same layout, rows m = n*1024+t)
//  k_cvt_h0   : h0 fp32 -> h16 buf0 fp16
//  k_tr_wx    : Wx (1024x4096) -> WxT fp16 (4096x1024)  [LDS tile transpose]
//  k_pack_wh  : Wh -> per-block/wave/fragment-ordered fp16 pack for register-resident B
//  k_gemm_xw  : xw16[t][n][4096] = x16 @ WxT^T   (m97-style 128x128x64 MFMA GEMM)
//  k_lstm     : persistent 64-block kernel, 1024 steps, custom device barrier.
//               Each block owns 16 h-cols (64 gate cols); Wh slice in VGPRs
//               (32KB/wave, K split 4 ways); LDS ds_add reduction; c in fp32 regs.

typedef _Float16 f16x8 __attribute__((ext_vector_type(8)));
typedef _Float16 f16x4 __attribute__((ext_vector_type(4)));
typedef float    f32x4 __attribute__((ext_vector_type(4)));

#define LN 64
#define LT 1024
#define LD 1024
#define LH 1024
#define G4 4096

// workspace layout (bytes)
#define OFF_BAR  ((size_t)0)
#define OFF_H16  ((size_t)4096)                              // 2 x 64 x 1024 fp16 ping-pong
#define OFF_X16  (OFF_H16 + (size_t)2*LN*LH*2)               // 266240
#define OFF_WXT  (OFF_X16 + (size_t)LN*LT*LD*2)              // + 134217728
#define OFF_WHP  (OFF_WXT + (size_t)LD*G4*2)                 // + 8388608
#define OFF_XW   (OFF_WHP + (size_t)LH*G4*2)                 // + 8388608
#define WS_NEED  (OFF_XW  + (size_t)LN*LT*G4*2)              // + 536870912  => ~656 MB

__device__ __forceinline__ float fast_sigmoid(float x) {
  float e = __expf(-fabsf(x));
  float s = __fdividef(e, 1.f + e);
  return x >= 0.f ? 1.f - s : s;
}
__device__ __forceinline__ float fast_tanh(float x) {
  float e = __expf(-2.f * fabsf(x));
  float t = __fdividef(1.f - e, 1.f + e);
  return x >= 0.f ? t : -t;
}

// ---------------- converts / packs ----------------

__global__ void k_cvt_x(const float* __restrict__ x, _Float16* __restrict__ x16) {
  size_t i = (size_t)blockIdx.x * 256 + threadIdx.x;   // one float4 per thread
  float4 v = ((const float4*)x)[i];
  f16x4 o;
  o[0] = (_Float16)v.x; o[1] = (_Float16)v.y; o[2] = (_Float16)v.z; o[3] = (_Float16)v.w;
  ((f16x4*)x16)[i] = o;
}

__global__ void k_cvt_h0(const float* __restrict__ h0, _Float16* __restrict__ h16) {
  int i = blockIdx.x * 256 + threadIdx.x;              // 65536 total
  h16[i] = (_Float16)h0[i];
}

__global__ void k_tr_wx(const float* __restrict__ Wx, _Float16* __restrict__ WxT) {
  __shared__ float tile[64][65];
  const int c0 = blockIdx.x * 64;   // col in 4096
  const int d0 = blockIdx.y * 64;   // row in 1024
  const int tx = threadIdx.x & 63, ty = threadIdx.x >> 6;
  for (int r = ty; r < 64; r += 4)
    tile[r][tx] = Wx[(size_t)(d0 + r) * G4 + c0 + tx];
  __syncthreads();
  for (int r = ty; r < 64; r += 4)
    WxT[(size_t)(c0 + r) * LD + d0 + tx] = (_Float16)tile[tx][r];
}

// dest unit u = (((bid*4 + w)*4 + g)*8 + kc)*64 + lane, each unit = 8 fp16 (16B)
__global__ void k_pack_wh(const float* __restrict__ Wh, _Float16* __restrict__ whp) {
  unsigned u = blockIdx.x * 256 + threadIdx.x;         // 524288 total
  int lane = u & 63; unsigned r = u >> 6;
  int kc = r & 7; r >>= 3;
  int g  = r & 3; r >>= 2;
  int w  = r & 3;
  int bid = r >> 2;
  int col = g * 1024 + bid * 16 + (lane & 15);
  int k0  = w * 256 + kc * 32 + (lane >> 4) * 8;
  f16x8 v;
#pragma unroll
  for (int j = 0; j < 8; ++j) v[j] = (_Float16)Wh[(size_t)(k0 + j) * G4 + col];
  ((f16x8*)whp)[u] = v;
}

// ---------------- phase-1 GEMM: xw = x @ Wx ----------------

__device__ __forceinline__ void gl_lds16(const _Float16* g, _Float16* l) {
  __builtin_amdgcn_global_load_lds(
      (const __attribute__((address_space(1))) unsigned int*)g,
      (__attribute__((address_space(3))) unsigned int*)l, 16, 0, 0);
}

__global__ __launch_bounds__(256) void k_gemm_xw(const _Float16* __restrict__ A,  // [65536][1024]
                                                 const _Float16* __restrict__ B,  // [4096][1024]
                                                 _Float16* __restrict__ C) {      // [t][n][4096]
  __shared__ _Float16 As[128 * 64];
  __shared__ _Float16 Bs[128 * 64];
  const int tid = threadIdx.x;
  const int lane = tid & 63;
  const int w = tid >> 6;
  const int wm = w & 1, wn = w >> 1;
  const int m0 = blockIdx.x * 128;
  const int n0 = blockIdx.y * 128;
  const int lr = lane >> 3;          // row 0..7 within an 8-row chunk
  const int lcb = (lane & 7) * 8;    // k element offset within 64

  f32x4 acc[4][4];
#pragma unroll
  for (int i = 0; i < 4; ++i)
#pragma unroll
    for (int j = 0; j < 4; ++j) acc[i][j] = (f32x4){0.f, 0.f, 0.f, 0.f};

  for (int kt = 0; kt < 16; ++kt) {
    const int k0 = kt * 64;
#pragma unroll
    for (int c2 = 0; c2 < 4; ++c2) {
      int chunk = w * 4 + c2;        // 0..15, 8 rows each
      int row = chunk * 8 + lr;
      gl_lds16(&A[(size_t)(m0 + row) * LD + k0 + lcb], &As[chunk * 512]);
      gl_lds16(&B[(size_t)(n0 + row) * LD + k0 + lcb], &Bs[chunk * 512]);
    }
    __syncthreads();
#pragma unroll
    for (int kc = 0; kc < 2; ++kc) {
      const int ko = kc * 32 + (lane >> 4) * 8;
      f16x8 Af[4], Bf[4];
#pragma unroll
      for (int mt = 0; mt < 4; ++mt)
        Af[mt] = *(const f16x8*)&As[(wm * 64 + mt * 16 + (lane & 15)) * 64 + ko];
#pragma unroll
      for (int nt = 0; nt < 4; ++nt)
        Bf[nt] = *(const f16x8*)&Bs[(wn * 64 + nt * 16 + (lane & 15)) * 64 + ko];
#pragma unroll
      for (int mt = 0; mt < 4; ++mt)
#pragma unroll
        for (int nt = 0; nt < 4; ++nt)
          acc[mt][nt] = __builtin_amdgcn_mfma_f32_16x16x32_f16(Af[mt], Bf[nt], acc[mt][nt], 0, 0, 0);
    }
    __syncthreads();
  }
  // epilogue: C[(t*64+n)*4096 + col] fp16, m = n*1024 + t
#pragma unroll
  for (int mt = 0; mt < 4; ++mt) {
#pragma unroll
    for (int nt = 0; nt < 4; ++nt) {
      int col = n0 + wn * 64 + nt * 16 + (lane & 15);
#pragma unroll
      for (int r = 0; r < 4; ++r) {
        int m = m0 + wm * 64 + mt * 16 + (lane >> 4) * 4 + r;
        int n = m >> 10, t = m & 1023;
        C[((size_t)t * 64 + n) * G4 + col] = (_Float16)acc[mt][nt][r];
      }
    }
  }
}

// ---------------- persistent recurrent kernel ----------------

__global__ __launch_bounds__(256, 1) void k_lstm(
    const _Float16* __restrict__ whp, const _Float16* __restrict__ xw,
    const float* __restrict__ bias, _Float16* h16, float* __restrict__ out,
    unsigned int* __restrict__ bar) {
  const int tid = threadIdx.x, bid = blockIdx.x;
  const int lane = tid & 63, w = tid >> 6;
  const int hx = tid & 15, b4 = tid >> 4;
  __shared__ float Ared[4096];   // [b 0..63][gcol 0..63] fp32

  // B fragments: Wh slice, register-resident for the whole kernel.
  f16x8 Bf[4][8];
  {
    const f16x8* bp = (const f16x8*)whp + ((size_t)(bid * 4 + w) * 32) * 64 + lane;
#pragma unroll
    for (int g = 0; g < 4; ++g)
#pragma unroll
      for (int kc = 0; kc < 8; ++kc) Bf[g][kc] = bp[(g * 8 + kc) * 64];
  }
  float bv[4];
#pragma unroll
  for (int g = 0; g < 4; ++g) bv[g] = bias[g * 1024 + bid * 16 + hx];
  float cst[4] = {0.f, 0.f, 0.f, 0.f};

  for (int i = tid; i < 1024; i += 256) ((f32x4*)Ared)[i] = (f32x4){0.f, 0.f, 0.f, 0.f};
  __syncthreads();

  const int arow = lane & 15;
  const int kbase = w * 256 + (lane >> 4) * 8;
  int p = 0;

  for (int t = 0; t < LT; ++t) {
    __builtin_amdgcn_fence(__ATOMIC_ACQUIRE, "agent");  // invalidate stale L1/L2 h lines

    // prefetch this step's xw slice (consumed after the reduce barrier)
    float xwv[4][4];
#pragma unroll
    for (int q = 0; q < 4; ++q)
#pragma unroll
      for (int g = 0; g < 4; ++g)
        xwv[q][g] = (float)xw[((size_t)t * 64 + b4 * 4 + q) * G4 + g * 1024 + bid * 16 + hx];

    const _Float16* hc = h16 + (size_t)p * (LN * LH);
    f32x4 acc[4][4];
#pragma unroll
    for (int i = 0; i < 4; ++i)
#pragma unroll
      for (int j = 0; j < 4; ++j) acc[i][j] = (f32x4){0.f, 0.f, 0.f, 0.f};

#pragma unroll
    for (int kc = 0; kc < 8; ++kc) {
      f16x8 Af[4];
#pragma unroll
      for (int mt = 0; mt < 4; ++mt)
        Af[mt] = *(const f16x8*)&hc[(mt * 16 + arow) * LH + kbase + kc * 32];
#pragma unroll
      for (int mt = 0; mt < 4; ++mt)
#pragma unroll
        for (int g = 0; g < 4; ++g)
          acc[mt][g] = __builtin_amdgcn_mfma_f32_16x16x32_f16(Af[mt], Bf[g][kc], acc[mt][g], 0, 0, 0);
    }

    // cross-wave K reduction via LDS atomic adds (staggered to cut collisions)
#pragma unroll
    for (int mi = 0; mi < 4; ++mi) {
      int mt = (mi + w) & 3;
#pragma unroll
      for (int gi = 0; gi < 4; ++gi) {
        int g = (gi + w) & 3;
#pragma unroll
        for (int r = 0; r < 4; ++r)
          atomicAdd(&Ared[(mt * 16 + (lane >> 4) * 4 + r) * 64 + g * 16 + (lane & 15)],
                    acc[mt][g][r]);
      }
    }
    __syncthreads();

    // gates: thread owns (b = b4*4+q, hcol = bid*16+hx), c state in registers
    _Float16* hn = h16 + (size_t)(p ^ 1) * (LN * LH);
#pragma unroll
    for (int q = 0; q < 4; ++q) {
      const int b = b4 * 4 + q;
      float Ai = Ared[b * 64 +  0 + hx] + xwv[q][0] + bv[0];
      float Af_ = Ared[b * 64 + 16 + hx] + xwv[q][1] + bv[1];
      float Ao = Ared[b * 64 + 32 + hx] + xwv[q][2] + bv[2];
      float Ag = Ared[b * 64 + 48 + hx] + xwv[q][3] + bv[3];
      float iv = fast_sigmoid(Ai), fv = fast_sigmoid(Af_), ov = fast_sigmoid(Ao);
      float gv = fast_tanh(Ag);
      float cn = fv * cst[q] + iv * gv;
      cst[q] = cn;
      float hv = ov * fast_tanh(cn);
      union { _Float16 h; unsigned short u; } cvt; cvt.h = (_Float16)hv;
      // agent-scope (write-through) store so other XCDs see fresh h next step
      __hip_atomic_store((unsigned short*)&hn[b * 1024 + bid * 16 + hx], cvt.u,
                         __ATOMIC_RELAXED, __HIP_MEMORY_SCOPE_AGENT);
      __builtin_nontemporal_store(hv, &out[((size_t)b * 1024 + t) * 1024 + bid * 16 + hx]);
    }
    __syncthreads();   // drains all waves' h stores (vmcnt0 before s_barrier) + Ared reads done

    if (tid == 0)
      __hip_atomic_fetch_add(bar, 1u, __ATOMIC_RELAXED, __HIP_MEMORY_SCOPE_AGENT);

    // overlap Ared re-zero with barrier propagation
    for (int i = tid; i < 1024; i += 256) ((f32x4*)Ared)[i] = (f32x4){0.f, 0.f, 0.f, 0.f};
    __syncthreads();

    if (tid == 0) {
      const unsigned tgt = 64u * (t + 1);
      while (__hip_atomic_load(bar, __ATOMIC_RELAXED, __HIP_MEMORY_SCOPE_AGENT) < tgt)
        __builtin_amdgcn_s_sleep(8);
    }
    __syncthreads();
    p ^= 1;
  }
}

// ---------------- launch ----------------

extern "C" void kernel_launch(void* const* d_in, const int* in_sizes, int n_in,
                              void* d_out, int out_size, void* d_ws, size_t ws_size,
                              hipStream_t stream) {
  const float* x  = (const float*)d_in[0];
  const float* h0 = (const float*)d_in[1];
  const float* Wx = (const float*)d_in[2];
  const float* Wh = (const float*)d_in[3];
  const float* b  = (const float*)d_in[4];
  float* out = (float*)d_out;
  char* ws = (char*)d_ws;
  if (ws_size < WS_NEED) return;  // insufficient scratch: bail (shows as poison absmax)

  unsigned int* bar = (unsigned int*)(ws + OFF_BAR);
  _Float16* h16 = (_Float16*)(ws + OFF_H16);
  _Float16* x16 = (_Float16*)(ws + OFF_X16);
  _Float16* wxT = (_Float16*)(ws + OFF_WXT);
  _Float16* whp = (_Float16*)(ws + OFF_WHP);
  _Float16* xw  = (_Float16*)(ws + OFF_XW);

  hipMemsetAsync(bar, 0, 256, stream);
  hipLaunchKernelGGL(k_cvt_x,   dim3(65536),   dim3(256), 0, stream, x, x16);
  hipLaunchKernelGGL(k_cvt_h0,  dim3(256),     dim3(256), 0, stream, h0, h16);
  hipLaunchKernelGGL(k_tr_wx,   dim3(64, 16),  dim3(256), 0, stream, Wx, wxT);
  hipLaunchKernelGGL(k_pack_wh, dim3(2048),    dim3(256), 0, stream, Wh, whp);
  hipLaunchKernelGGL(k_gemm_xw, dim3(512, 32), dim3(256), 0, stream, x16, wxT, xw);
  hipLaunchKernelGGL(k_lstm,    dim3(64),      dim3(256), 0, stream, whp, xw, b, h16, out, bar);
}